// Round 14
// baseline (146.778 us; speedup 1.0000x reference)
//
#include <hip/hip_runtime.h>
#include <hip/hip_bf16.h>

#define BB 16
#define CC 192
#define TPIX 3136                       // 56*56
#define NCH 98                          // chunks per sequence
#define CHL 32                          // chunk length (98*32 = 3136)
#define NNELE ((size_t)BB * TPIX * CC)  // 9,633,792 elements per [B,T,C] buffer
#define NSTATE ((size_t)2 * BB * NCH * CC)  // 602,112 chunk states
#define WCH (CC * CC)                   // 36864 elems per W matrix

typedef __attribute__((ext_vector_type(8))) short bf16x8;
typedef __attribute__((ext_vector_type(4))) float f32x4;
typedef __attribute__((ext_vector_type(16))) float f32x16;

__device__ __forceinline__ unsigned short f2bf(float f) {
    __hip_bfloat16 b = __float2bfloat16(f);          // HW RNE cvt
    return *reinterpret_cast<unsigned short*>(&b);
}
__device__ __forceinline__ float bf2f(unsigned short h) {
    union { unsigned u; float f; } v; v.u = ((unsigned)h) << 16;
    return v.f;
}

// Fragment-major layout: element (row, col) of a rows x 192 matrix lives at
//   tile = (row>>5)*12 + (col>>4);  lane = (row&31) + ((col>>3)&1)*32;  elem = col&7
//   offset = tile*512 + lane*8 + elem

// ---------------------------------------------------------------------------
// W convert -> fragment-major bf16, 4 matrices (k,v,r,o).
// ---------------------------------------------------------------------------
__global__ __launch_bounds__(256) void wcvt_frag(
    const float* __restrict__ Wk, const float* __restrict__ Wv,
    const float* __restrict__ Wr, const float* __restrict__ Wo,
    unsigned short* __restrict__ wfrag)
{
    const int id = blockIdx.x * 256 + threadIdx.x;    // 0..18431
    const int m = id / 4608;
    const int r = id % 4608;
    const int tile = r >> 6;          // 0..71  (= dr*12 + tk)
    const int lane = r & 63;
    const int dr = tile / 12, tk = tile % 12;
    const int d = dr * 32 + (lane & 31);
    const int c = tk * 16 + (lane >> 5) * 8;
    const float* W = (m == 0) ? Wk : (m == 1) ? Wv : (m == 2) ? Wr : Wo;
    const float4 a = *(const float4*)&W[d * CC + c];
    const float4 b = *(const float4*)&W[d * CC + c + 4];
    bf16x8 o;
    o[0] = (short)f2bf(a.x); o[1] = (short)f2bf(a.y);
    o[2] = (short)f2bf(a.z); o[3] = (short)f2bf(a.w);
    o[4] = (short)f2bf(b.x); o[5] = (short)f2bf(b.y);
    o[6] = (short)f2bf(b.z); o[7] = (short)f2bf(b.w);
    *(bf16x8*)&wfrag[(size_t)m * WCH + (size_t)tile * 512 + lane * 8] = o;
}

// ---------------------------------------------------------------------------
// x transpose+convert -> fragment-major bf16. Block = 32 t x 192 c for one b.
// ---------------------------------------------------------------------------
__global__ __launch_bounds__(256) void xcvt_frag(
    const float* __restrict__ x, unsigned short* __restrict__ xfrag)
{
    const int t0 = blockIdx.x * 32;
    const int b  = blockIdx.y;
    __shared__ float ls[CC][33];
    const int tid = threadIdx.x;
#pragma unroll
    for (int it = 0; it < 6; ++it) {
        const int c  = it * 32 + (tid >> 3);
        const int t4 = (tid & 7) * 4;
        *(float4*)&ls[c][t4] =
            *(const float4*)&x[((size_t)b * CC + c) * TPIX + t0 + t4];
    }
    __syncthreads();
    const size_t tbase = ((size_t)(b * TPIX + t0) >> 5) * 12;
#pragma unroll
    for (int it = 0; it < 3; ++it) {
        const int id = it * 256 + tid;          // 0..767
        const int tk = id >> 6;
        const int lane = id & 63;
        const int r32 = lane & 31;
        const int c0 = tk * 16 + (lane >> 5) * 8;
        bf16x8 o;
#pragma unroll
        for (int e = 0; e < 8; ++e)
            o[e] = (short)f2bf(ls[c0 + e][r32]);
        *(bf16x8*)&xfrag[(tbase + tk) * 512 + lane * 8] = o;
    }
}

// ---------------------------------------------------------------------------
// Fused projections, 32x32x16 MFMA. Full W_m staged in LDS (fragment-major);
// x streamed with depth-1 prefetch. mfma(xf, wf): D lane = d, regs = t ->
// contiguous 64B store segments per half-wave.
// Block = 8 waves = 128 t x 192 d; wave = 32 t x 96 d. grid (392, 1, 3) x 512.
// ---------------------------------------------------------------------------
__global__ __launch_bounds__(512) void proj_mfma32(
    const unsigned short* __restrict__ xfrag,
    const unsigned short* __restrict__ wfrag,
    unsigned short* __restrict__ kbf, unsigned short* __restrict__ vbf,
    unsigned short* __restrict__ rbf)
{
    __shared__ unsigned short wlds[WCH];     // 73728 bytes
    const int tid  = threadIdx.x;
    const int lane = tid & 63;
    const int wv   = tid >> 6;               // 0..7
    const int tw   = wv >> 1;                // 0..3
    const int dwav = wv & 1;
    const int l31  = lane & 31;
    const int kh   = lane >> 5;
    const int m    = blockIdx.z;

    const unsigned short* wm = wfrag + (size_t)m * WCH;
#pragma unroll
    for (int it = 0; it < 9; ++it) {
        const int off = (it * 512 + tid) * 8;
        *(bf16x8*)&wlds[off] = *(const bf16x8*)&wm[off];
    }
    __syncthreads();

    const size_t row0 = (size_t)blockIdx.x * 128 + tw * 32;
    const size_t xtb  = (row0 >> 5) * 12;

    f32x16 acc[3];
#pragma unroll
    for (int nn = 0; nn < 3; ++nn)
#pragma unroll
        for (int e = 0; e < 16; ++e) acc[nn][e] = 0.f;

    bf16x8 xf = *(const bf16x8*)&xfrag[xtb * 512 + lane * 8];
#pragma unroll
    for (int ks = 0; ks < 12; ++ks) {
        bf16x8 nxf;
        if (ks < 11)
            nxf = *(const bf16x8*)&xfrag[(xtb + ks + 1) * 512 + lane * 8];
        bf16x8 wf[3];
#pragma unroll
        for (int nn = 0; nn < 3; ++nn)
            wf[nn] = *(const bf16x8*)&wlds[((dwav * 3 + nn) * 12 + ks) * 512 + lane * 8];
#pragma unroll
        for (int nn = 0; nn < 3; ++nn)
            acc[nn] = __builtin_amdgcn_mfma_f32_32x32x16_bf16(
                xf, wf[nn], acc[nn], 0, 0, 0);
        if (ks < 11) xf = nxf;
    }

    unsigned short* om = (m == 0) ? kbf : (m == 1) ? vbf : rbf;
#pragma unroll
    for (int nn = 0; nn < 3; ++nn) {
        const int d = dwav * 96 + nn * 32 + l31;
#pragma unroll
        for (int q = 0; q < 16; ++q) {
            const int t = (q & 3) + 8 * (q >> 2) + 4 * kh;
            om[(row0 + t) * CC + d] = f2bf(acc[nn][q]);
        }
    }
}

// ---------------------------------------------------------------------------
// Output projection, 32x32x16 MFMA. Wo staged in LDS; h streamed (prefetch).
// mfma(hf, wf): lane = d, reg quads = consecutive t -> f32x4 stores into
// transposed [b][d][t] output. Block 8 waves; grid 392 x 512.
// ---------------------------------------------------------------------------
__global__ __launch_bounds__(512) void outproj_mfma32(
    const unsigned short* __restrict__ hfrag,
    const unsigned short* __restrict__ wo,
    float* __restrict__ out)
{
    __shared__ unsigned short wlds[WCH];
    const int tid  = threadIdx.x;
    const int lane = tid & 63;
    const int wv   = tid >> 6;
    const int tw   = wv >> 1;
    const int dwav = wv & 1;
    const int l31  = lane & 31;
    const int kh   = lane >> 5;

#pragma unroll
    for (int it = 0; it < 9; ++it) {
        const int off = (it * 512 + tid) * 8;
        *(bf16x8*)&wlds[off] = *(const bf16x8*)&wo[off];
    }
    __syncthreads();

    const size_t row0 = (size_t)blockIdx.x * 128 + tw * 32;
    const size_t htb  = (row0 >> 5) * 12;

    f32x16 acc[3];
#pragma unroll
    for (int nn = 0; nn < 3; ++nn)
#pragma unroll
        for (int e = 0; e < 16; ++e) acc[nn][e] = 0.f;

    bf16x8 hf = *(const bf16x8*)&hfrag[htb * 512 + lane * 8];
#pragma unroll
    for (int ks = 0; ks < 12; ++ks) {
        bf16x8 nhf;
        if (ks < 11)
            nhf = *(const bf16x8*)&hfrag[(htb + ks + 1) * 512 + lane * 8];
        bf16x8 wf[3];
#pragma unroll
        for (int nn = 0; nn < 3; ++nn)
            wf[nn] = *(const bf16x8*)&wlds[((dwav * 3 + nn) * 12 + ks) * 512 + lane * 8];
#pragma unroll
        for (int nn = 0; nn < 3; ++nn)
            acc[nn] = __builtin_amdgcn_mfma_f32_32x32x16_bf16(
                hf, wf[nn], acc[nn], 0, 0, 0);
        if (ks < 11) hf = nhf;
    }

#pragma unroll
    for (int nn = 0; nn < 3; ++nn) {
        const int d = dwav * 96 + nn * 32 + l31;
#pragma unroll
        for (int q2 = 0; q2 < 4; ++q2) {
            const size_t grow = row0 + 4 * kh + 8 * q2;
            const int b  = (int)(grow / TPIX);
            const int tl = (int)(grow % TPIX);
            f32x4 v4 = {acc[nn][q2 * 4 + 0], acc[nn][q2 * 4 + 1],
                        acc[nn][q2 * 4 + 2], acc[nn][q2 * 4 + 3]};
            *(f32x4*)&out[((size_t)b * CC + d) * TPIX + tl] = v4;
        }
    }
}

// ---------------------------------------------------------------------------
// WKV chunked scan pass 1 (bf16 k/v, [t][c] layout). (num,den)=(p,q)*e^o.
// CHL=32 -> 602K threads, ~8 waves/SIMD of TLP for the latency chain.
// ---------------------------------------------------------------------------
__global__ __launch_bounds__(256) void wkv_chunk_kernel(
    const unsigned short* __restrict__ kb, const unsigned short* __restrict__ vb,
    const float* __restrict__ wdec,
    float* __restrict__ sp, float* __restrict__ sq, float* __restrict__ so)
{
    const int gid = blockIdx.x * 256 + threadIdx.x;
    const int c  = gid % CC;
    const int r  = gid / CC;
    const int ch = r % NCH;
    const int r2 = r / NCH;
    const int b  = r2 % BB;
    const int dir = r2 / BB;

    const float w = -__expf(wdec[c]);
    const int tstart = dir ? (TPIX - 1 - ch * CHL) : (ch * CHL);
    const long stride = dir ? -(long)CC : (long)CC;
    long idx = ((long)b * TPIX + tstart) * CC + c;

    float p = 0.f, q = 0.f, o = -1e38f;
#pragma unroll 4
    for (int j = 0; j < CHL; ++j) {
        const float kt = bf2f(kb[idx]), vt = bf2f(vb[idx]);
        const float wo  = w + o;
        const float no2 = fmaxf(wo, kt);
        const float A2  = __expf(wo - no2);
        const float B2  = __expf(kt - no2);
        p = A2 * p + B2 * vt;
        q = A2 * q + B2;
        o = no2;
        idx += stride;
    }
    sp[gid] = p; sq[gid] = q; so[gid] = o;
}

// Pass 2: in-place exclusive prefix over 98 chunk states per (dir,b,c).
__global__ __launch_bounds__(256) void wkv_prefix_kernel(
    float* __restrict__ sp, float* __restrict__ sq, float* __restrict__ so,
    const float* __restrict__ wdec)
{
    const int tid = blockIdx.x * 256 + threadIdx.x;
    if (tid >= 2 * BB * CC) return;
    const int c = tid % CC;
    const int g = tid / CC;
    const float w  = -__expf(wdec[c]);
    const float wL = w * CHL;

    float P = 0.f, Q = 0.f, O = -1e38f;
    size_t idx = (size_t)g * NCH * CC + c;
    for (int ch = 0; ch < NCH; ++ch) {
        const float pl = sp[idx], ql = sq[idx], ol = so[idx];
        sp[idx] = P; sq[idx] = Q; so[idx] = O;
        const float Ow = O + wL;
        const float no = fmaxf(Ow, ol);
        const float A  = __expf(Ow - no);
        const float Bf = __expf(ol - no);
        P = A * P + Bf * pl;
        Q = A * Q + Bf * ql;
        O = no;
        idx += CC;
    }
}

// Pass 3: re-scan chunk from exclusive prefix; write bf16(0.5*y) to the
// direction's own buffer (plain stores, each element once -> deterministic).
__global__ __launch_bounds__(256) void wkv_emit_kernel(
    const unsigned short* __restrict__ kb, const unsigned short* __restrict__ vb,
    const float* __restrict__ wdec, const float* __restrict__ ubias,
    const float* __restrict__ sp, const float* __restrict__ sq,
    const float* __restrict__ so,
    unsigned short* __restrict__ yfwd, unsigned short* __restrict__ ybwd)
{
    const int gid = blockIdx.x * 256 + threadIdx.x;
    const int c  = gid % CC;
    const int r  = gid / CC;
    const int ch = r % NCH;
    const int r2 = r / NCH;
    const int b  = r2 % BB;
    const int dir = r2 / BB;

    const float w = -__expf(wdec[c]);
    const float u = ubias[c];
    const int tstart = dir ? (TPIX - 1 - ch * CHL) : (ch * CHL);
    const long stride = dir ? -(long)CC : (long)CC;
    long idx = ((long)b * TPIX + tstart) * CC + c;
    unsigned short* yout = dir ? ybwd : yfwd;

    float p = sp[gid], q = sq[gid], o = so[gid];
#pragma unroll 2
    for (int j = 0; j < CHL; ++j) {
        const float kt = bf2f(kb[idx]), vt = bf2f(vb[idx]);
        const float uk  = u + kt;
        const float no  = fmaxf(o, uk);
        const float A   = __expf(o - no);
        const float Bw  = __expf(uk - no);
        const float num = A * p + Bw * vt;
        const float den = A * q + Bw;
        yout[idx] = f2bf(0.5f * __fdividef(num, den));
        const float wo  = w + o;
        const float no2 = fmaxf(wo, kt);
        const float A2  = __expf(wo - no2);
        const float B2  = __expf(kt - no2);
        p = A2 * p + B2 * vt;
        q = A2 * q + B2;
        o = no2;
        idx += stride;
    }
}

// ---------------------------------------------------------------------------
// h = LN( sigmoid(r) * (yf + yb) ) over C; writes h in fragment-major bf16.
// ---------------------------------------------------------------------------
__global__ __launch_bounds__(192) void ln_kernel(
    const unsigned short* __restrict__ rbf,
    const unsigned short* __restrict__ yfwd, const unsigned short* __restrict__ ybwd,
    const float* __restrict__ gamma, const float* __restrict__ beta,
    unsigned short* __restrict__ hfrag)
{
    const size_t row = blockIdx.x;
    const int c = threadIdx.x;
    const size_t idx = row * CC + c;
    const float rv = bf2f(rbf[idx]);
    const float xb = bf2f(yfwd[idx]) + bf2f(ybwd[idx]);
    const float hv = xb / (1.f + __expf(-rv));
    float s = hv, s2 = hv * hv;
#pragma unroll
    for (int off = 1; off < 64; off <<= 1) {
        s  += __shfl_xor(s, off);
        s2 += __shfl_xor(s2, off);
    }
    __shared__ float red[2][3];
    const int wv = threadIdx.x >> 6;
    if ((threadIdx.x & 63) == 0) { red[0][wv] = s; red[1][wv] = s2; }
    __syncthreads();
    s  = red[0][0] + red[0][1] + red[0][2];
    s2 = red[1][0] + red[1][1] + red[1][2];
    const float mu   = s * (1.f / CC);
    const float var  = s2 * (1.f / CC) - mu * mu;
    const float rstd = rsqrtf(var + 1e-5f);
    const float hval = (hv - mu) * rstd * gamma[c] + beta[c];
    const size_t off = ((row >> 5) * 12 + (c >> 4)) * 512 +
                       ((row & 31) + ((c >> 3) & 1) * 32) * 8 + (c & 7);
    hfrag[off] = f2bf(hval);
}

// ---------------------------------------------------------------------------
extern "C" void kernel_launch(void* const* d_in, const int* in_sizes, int n_in,
                              void* d_out, int out_size, void* d_ws, size_t ws_size,
                              hipStream_t stream)
{
    const float* x    = (const float*)d_in[0];
    const float* Wk   = (const float*)d_in[1];
    const float* Wv   = (const float*)d_in[2];
    const float* Wr   = (const float*)d_in[3];
    const float* Wo   = (const float*)d_in[4];
    const float* ln_g = (const float*)d_in[5];
    const float* ln_b = (const float*)d_in[6];
    const float* wdec = (const float*)d_in[7];
    const float* u    = (const float*)d_in[8];

    unsigned short* kbf   = (unsigned short*)d_ws;
    unsigned short* vbf   = kbf + NNELE;
    unsigned short* rbf   = vbf + NNELE;
    unsigned short* xfrag = rbf + NNELE;
    unsigned short* wfrag = xfrag + NNELE;       // 4*WCH bf16
    float* sp = (float*)xfrag;                   // alias: states after proj (7.2MB < 19.3MB)
    float* sq = sp + NSTATE;
    float* so = sq + NSTATE;
    unsigned short* hfrag = kbf;                 // alias: h after scans
    unsigned short* yfwd  = (unsigned short*)d_out;  // bf16 staging in d_out
    unsigned short* ybwd  = yfwd + NNELE;
    float* out = (float*)d_out;

    wcvt_frag<<<72, 256, 0, stream>>>(Wk, Wv, Wr, Wo, wfrag);
    xcvt_frag<<<dim3(TPIX / 32, BB), 256, 0, stream>>>(x, xfrag);

    proj_mfma32<<<dim3((BB * TPIX) / 128, 1, 3), 512, 0, stream>>>(
        xfrag, wfrag, kbf, vbf, rbf);

    const int nth = (int)NSTATE;                 // 602,112
    wkv_chunk_kernel<<<nth / 256, 256, 0, stream>>>(kbf, vbf, wdec, sp, sq, so);
    wkv_prefix_kernel<<<(2 * BB * CC + 255) / 256, 256, 0, stream>>>(sp, sq, so, wdec);
    wkv_emit_kernel<<<nth / 256, 256, 0, stream>>>(kbf, vbf, wdec, u, sp, sq, so, yfwd, ybwd);

    ln_kernel<<<BB * TPIX, 192, 0, stream>>>(rbf, yfwd, ybwd, ln_g, ln_b, hfrag);

    outproj_mfma32<<<(BB * TPIX) / 128, 512, 0, stream>>>(hfrag, wfrag + 3 * WCH, out);
}

// Round 15
// 135.594 us; speedup vs baseline: 1.0825x; 1.0825x over previous
//
#include <hip/hip_runtime.h>
#include <hip/hip_bf16.h>

#define BB 16
#define CC 192
#define TPIX 3136                       // 56*56
#define NCH 49                          // chunks per sequence
#define CHL 64                          // chunk length (49*64 = 3136)
#define NNELE ((size_t)BB * TPIX * CC)  // 9,633,792 elements per [B,T,C] buffer
#define NSTATE ((size_t)2 * BB * NCH * CC)  // 301,056 chunk states
#define WCH (CC * CC)                   // 36864 elems per W matrix

typedef __attribute__((ext_vector_type(8))) short bf16x8;
typedef __attribute__((ext_vector_type(4))) float f32x4;
typedef __attribute__((ext_vector_type(16))) float f32x16;

__device__ __forceinline__ unsigned short f2bf(float f) {
    __hip_bfloat16 b = __float2bfloat16(f);          // HW RNE cvt
    return *reinterpret_cast<unsigned short*>(&b);
}
__device__ __forceinline__ float bf2f(unsigned short h) {
    union { unsigned u; float f; } v; v.u = ((unsigned)h) << 16;
    return v.f;
}

// Fragment-major layout: element (row, col) of a rows x 192 matrix lives at
//   tile = (row>>5)*12 + (col>>4);  lane = (row&31) + ((col>>3)&1)*32;  elem = col&7
//   offset = tile*512 + lane*8 + elem

// ---------------------------------------------------------------------------
// W convert -> fragment-major bf16, 4 matrices (k,v,r,o).
// ---------------------------------------------------------------------------
__global__ __launch_bounds__(256) void wcvt_frag(
    const float* __restrict__ Wk, const float* __restrict__ Wv,
    const float* __restrict__ Wr, const float* __restrict__ Wo,
    unsigned short* __restrict__ wfrag)
{
    const int id = blockIdx.x * 256 + threadIdx.x;    // 0..18431
    const int m = id / 4608;
    const int r = id % 4608;
    const int tile = r >> 6;          // 0..71  (= dr*12 + tk)
    const int lane = r & 63;
    const int dr = tile / 12, tk = tile % 12;
    const int d = dr * 32 + (lane & 31);
    const int c = tk * 16 + (lane >> 5) * 8;
    const float* W = (m == 0) ? Wk : (m == 1) ? Wv : (m == 2) ? Wr : Wo;
    const float4 a = *(const float4*)&W[d * CC + c];
    const float4 b = *(const float4*)&W[d * CC + c + 4];
    bf16x8 o;
    o[0] = (short)f2bf(a.x); o[1] = (short)f2bf(a.y);
    o[2] = (short)f2bf(a.z); o[3] = (short)f2bf(a.w);
    o[4] = (short)f2bf(b.x); o[5] = (short)f2bf(b.y);
    o[6] = (short)f2bf(b.z); o[7] = (short)f2bf(b.w);
    *(bf16x8*)&wfrag[(size_t)m * WCH + (size_t)tile * 512 + lane * 8] = o;
}

// ---------------------------------------------------------------------------
// x transpose+convert -> fragment-major bf16. Block = 32 t x 192 c for one b.
// ---------------------------------------------------------------------------
__global__ __launch_bounds__(256) void xcvt_frag(
    const float* __restrict__ x, unsigned short* __restrict__ xfrag)
{
    const int t0 = blockIdx.x * 32;
    const int b  = blockIdx.y;
    __shared__ float ls[CC][33];
    const int tid = threadIdx.x;
#pragma unroll
    for (int it = 0; it < 6; ++it) {
        const int c  = it * 32 + (tid >> 3);
        const int t4 = (tid & 7) * 4;
        *(float4*)&ls[c][t4] =
            *(const float4*)&x[((size_t)b * CC + c) * TPIX + t0 + t4];
    }
    __syncthreads();
    const size_t tbase = ((size_t)(b * TPIX + t0) >> 5) * 12;
#pragma unroll
    for (int it = 0; it < 3; ++it) {
        const int id = it * 256 + tid;          // 0..767
        const int tk = id >> 6;
        const int lane = id & 63;
        const int r32 = lane & 31;
        const int c0 = tk * 16 + (lane >> 5) * 8;
        bf16x8 o;
#pragma unroll
        for (int e = 0; e < 8; ++e)
            o[e] = (short)f2bf(ls[c0 + e][r32]);
        *(bf16x8*)&xfrag[(tbase + tk) * 512 + lane * 8] = o;
    }
}

// ---------------------------------------------------------------------------
// Fused projections, 32x32x16 MFMA. ALL 12 x-fragments issued up front (48
// VGPRs) so their L3 latency hides under the 73.7KB W staging + barrier; the
// inner loop is then pure LDS+MFMA with no global waits.
// mfma(xf, wf): D lane = d, regs = t. Block = 8 waves = 128 t x 192 d;
// wave = 32 t x 96 d. grid (392, 1, 3) x 512.
// ---------------------------------------------------------------------------
__global__ __launch_bounds__(512, 4) void proj_mfma32(
    const unsigned short* __restrict__ xfrag,
    const unsigned short* __restrict__ wfrag,
    unsigned short* __restrict__ kbf, unsigned short* __restrict__ vbf,
    unsigned short* __restrict__ rbf)
{
    __shared__ unsigned short wlds[WCH];     // 73728 bytes
    const int tid  = threadIdx.x;
    const int lane = tid & 63;
    const int wv   = tid >> 6;               // 0..7
    const int tw   = wv >> 1;                // 0..3
    const int dwav = wv & 1;
    const int l31  = lane & 31;
    const int kh   = lane >> 5;
    const int m    = blockIdx.z;

    const size_t row0 = (size_t)blockIdx.x * 128 + tw * 32;
    const size_t xtb  = (row0 >> 5) * 12;

    // issue all 12 A-fragment loads first (oldest in the vmcnt queue)
    bf16x8 xf[12];
#pragma unroll
    for (int ks = 0; ks < 12; ++ks)
        xf[ks] = *(const bf16x8*)&xfrag[(xtb + ks) * 512 + lane * 8];

    // stage W; its ds_writes + barrier absorb the xf latency
    const unsigned short* wm = wfrag + (size_t)m * WCH;
#pragma unroll
    for (int it = 0; it < 9; ++it) {
        const int off = (it * 512 + tid) * 8;
        *(bf16x8*)&wlds[off] = *(const bf16x8*)&wm[off];
    }
    __syncthreads();

    f32x16 acc[3];
#pragma unroll
    for (int nn = 0; nn < 3; ++nn)
#pragma unroll
        for (int e = 0; e < 16; ++e) acc[nn][e] = 0.f;

#pragma unroll
    for (int ks = 0; ks < 12; ++ks) {
        bf16x8 wf[3];
#pragma unroll
        for (int nn = 0; nn < 3; ++nn)
            wf[nn] = *(const bf16x8*)&wlds[((dwav * 3 + nn) * 12 + ks) * 512 + lane * 8];
#pragma unroll
        for (int nn = 0; nn < 3; ++nn)
            acc[nn] = __builtin_amdgcn_mfma_f32_32x32x16_bf16(
                xf[ks], wf[nn], acc[nn], 0, 0, 0);
    }

    unsigned short* om = (m == 0) ? kbf : (m == 1) ? vbf : rbf;
#pragma unroll
    for (int nn = 0; nn < 3; ++nn) {
        const int d = dwav * 96 + nn * 32 + l31;
#pragma unroll
        for (int q = 0; q < 16; ++q) {
            const int t = (q & 3) + 8 * (q >> 2) + 4 * kh;
            om[(row0 + t) * CC + d] = f2bf(acc[nn][q]);
        }
    }
}

// ---------------------------------------------------------------------------
// Output projection, 32x32x16 MFMA. Same upfront-12 prefetch of h-fragments
// overlapped with Wo staging. mfma(hf, wf): lane = d, reg quads = consecutive
// t -> f32x4 stores into transposed [b][d][t] output. grid 392 x 512.
// ---------------------------------------------------------------------------
__global__ __launch_bounds__(512, 4) void outproj_mfma32(
    const unsigned short* __restrict__ hfrag,
    const unsigned short* __restrict__ wo,
    float* __restrict__ out)
{
    __shared__ unsigned short wlds[WCH];
    const int tid  = threadIdx.x;
    const int lane = tid & 63;
    const int wv   = tid >> 6;
    const int tw   = wv >> 1;
    const int dwav = wv & 1;
    const int l31  = lane & 31;
    const int kh   = lane >> 5;

    const size_t row0 = (size_t)blockIdx.x * 128 + tw * 32;
    const size_t htb  = (row0 >> 5) * 12;

    bf16x8 hf[12];
#pragma unroll
    for (int ks = 0; ks < 12; ++ks)
        hf[ks] = *(const bf16x8*)&hfrag[(htb + ks) * 512 + lane * 8];

#pragma unroll
    for (int it = 0; it < 9; ++it) {
        const int off = (it * 512 + tid) * 8;
        *(bf16x8*)&wlds[off] = *(const bf16x8*)&wo[off];
    }
    __syncthreads();

    f32x16 acc[3];
#pragma unroll
    for (int nn = 0; nn < 3; ++nn)
#pragma unroll
        for (int e = 0; e < 16; ++e) acc[nn][e] = 0.f;

#pragma unroll
    for (int ks = 0; ks < 12; ++ks) {
        bf16x8 wf[3];
#pragma unroll
        for (int nn = 0; nn < 3; ++nn)
            wf[nn] = *(const bf16x8*)&wlds[((dwav * 3 + nn) * 12 + ks) * 512 + lane * 8];
#pragma unroll
        for (int nn = 0; nn < 3; ++nn)
            acc[nn] = __builtin_amdgcn_mfma_f32_32x32x16_bf16(
                hf[ks], wf[nn], acc[nn], 0, 0, 0);
    }

#pragma unroll
    for (int nn = 0; nn < 3; ++nn) {
        const int d = dwav * 96 + nn * 32 + l31;
#pragma unroll
        for (int q2 = 0; q2 < 4; ++q2) {
            const size_t grow = row0 + 4 * kh + 8 * q2;
            const int b  = (int)(grow / TPIX);
            const int tl = (int)(grow % TPIX);
            f32x4 v4 = {acc[nn][q2 * 4 + 0], acc[nn][q2 * 4 + 1],
                        acc[nn][q2 * 4 + 2], acc[nn][q2 * 4 + 3]};
            *(f32x4*)&out[((size_t)b * CC + d) * TPIX + tl] = v4;
        }
    }
}

// ---------------------------------------------------------------------------
// WKV chunked scan pass 1 (bf16 k/v, [t][c] layout). (num,den)=(p,q)*e^o.
// ---------------------------------------------------------------------------
__global__ __launch_bounds__(256) void wkv_chunk_kernel(
    const unsigned short* __restrict__ kb, const unsigned short* __restrict__ vb,
    const float* __restrict__ wdec,
    float* __restrict__ sp, float* __restrict__ sq, float* __restrict__ so)
{
    const int gid = blockIdx.x * 256 + threadIdx.x;
    const int c  = gid % CC;
    const int r  = gid / CC;
    const int ch = r % NCH;
    const int r2 = r / NCH;
    const int b  = r2 % BB;
    const int dir = r2 / BB;

    const float w = -__expf(wdec[c]);
    const int tstart = dir ? (TPIX - 1 - ch * CHL) : (ch * CHL);
    const long stride = dir ? -(long)CC : (long)CC;
    long idx = ((long)b * TPIX + tstart) * CC + c;

    float p = 0.f, q = 0.f, o = -1e38f;
#pragma unroll 4
    for (int j = 0; j < CHL; ++j) {
        const float kt = bf2f(kb[idx]), vt = bf2f(vb[idx]);
        const float wo  = w + o;
        const float no2 = fmaxf(wo, kt);
        const float A2  = __expf(wo - no2);
        const float B2  = __expf(kt - no2);
        p = A2 * p + B2 * vt;
        q = A2 * q + B2;
        o = no2;
        idx += stride;
    }
    sp[gid] = p; sq[gid] = q; so[gid] = o;
}

// Pass 2: in-place exclusive prefix over chunk states per (dir,b,c).
__global__ __launch_bounds__(256) void wkv_prefix_kernel(
    float* __restrict__ sp, float* __restrict__ sq, float* __restrict__ so,
    const float* __restrict__ wdec)
{
    const int tid = blockIdx.x * 256 + threadIdx.x;
    if (tid >= 2 * BB * CC) return;
    const int c = tid % CC;
    const int g = tid / CC;
    const float w  = -__expf(wdec[c]);
    const float wL = w * CHL;

    float P = 0.f, Q = 0.f, O = -1e38f;
    size_t idx = (size_t)g * NCH * CC + c;
    for (int ch = 0; ch < NCH; ++ch) {
        const float pl = sp[idx], ql = sq[idx], ol = so[idx];
        sp[idx] = P; sq[idx] = Q; so[idx] = O;
        const float Ow = O + wL;
        const float no = fmaxf(Ow, ol);
        const float A  = __expf(Ow - no);
        const float Bf = __expf(ol - no);
        P = A * P + Bf * pl;
        Q = A * Q + Bf * ql;
        O = no;
        idx += CC;
    }
}

// Pass 3: re-scan chunk from exclusive prefix; write bf16(0.5*y) to the
// direction's own buffer (plain stores, each element once -> deterministic).
__global__ __launch_bounds__(256) void wkv_emit_kernel(
    const unsigned short* __restrict__ kb, const unsigned short* __restrict__ vb,
    const float* __restrict__ wdec, const float* __restrict__ ubias,
    const float* __restrict__ sp, const float* __restrict__ sq,
    const float* __restrict__ so,
    unsigned short* __restrict__ yfwd, unsigned short* __restrict__ ybwd)
{
    const int gid = blockIdx.x * 256 + threadIdx.x;
    const int c  = gid % CC;
    const int r  = gid / CC;
    const int ch = r % NCH;
    const int r2 = r / NCH;
    const int b  = r2 % BB;
    const int dir = r2 / BB;

    const float w = -__expf(wdec[c]);
    const float u = ubias[c];
    const int tstart = dir ? (TPIX - 1 - ch * CHL) : (ch * CHL);
    const long stride = dir ? -(long)CC : (long)CC;
    long idx = ((long)b * TPIX + tstart) * CC + c;
    unsigned short* yout = dir ? ybwd : yfwd;

    float p = sp[gid], q = sq[gid], o = so[gid];
#pragma unroll 2
    for (int j = 0; j < CHL; ++j) {
        const float kt = bf2f(kb[idx]), vt = bf2f(vb[idx]);
        const float uk  = u + kt;
        const float no  = fmaxf(o, uk);
        const float A   = __expf(o - no);
        const float Bw  = __expf(uk - no);
        const float num = A * p + Bw * vt;
        const float den = A * q + Bw;
        yout[idx] = f2bf(0.5f * __fdividef(num, den));
        const float wo  = w + o;
        const float no2 = fmaxf(wo, kt);
        const float A2  = __expf(wo - no2);
        const float B2  = __expf(kt - no2);
        p = A2 * p + B2 * vt;
        q = A2 * q + B2;
        o = no2;
        idx += stride;
    }
}

// ---------------------------------------------------------------------------
// h = LN( sigmoid(r) * (yf + yb) ) over C; writes h in fragment-major bf16.
// ---------------------------------------------------------------------------
__global__ __launch_bounds__(192) void ln_kernel(
    const unsigned short* __restrict__ rbf,
    const unsigned short* __restrict__ yfwd, const unsigned short* __restrict__ ybwd,
    const float* __restrict__ gamma, const float* __restrict__ beta,
    unsigned short* __restrict__ hfrag)
{
    const size_t row = blockIdx.x;
    const int c = threadIdx.x;
    const size_t idx = row * CC + c;
    const float rv = bf2f(rbf[idx]);
    const float xb = bf2f(yfwd[idx]) + bf2f(ybwd[idx]);
    const float hv = xb / (1.f + __expf(-rv));
    float s = hv, s2 = hv * hv;
#pragma unroll
    for (int off = 1; off < 64; off <<= 1) {
        s  += __shfl_xor(s, off);
        s2 += __shfl_xor(s2, off);
    }
    __shared__ float red[2][3];
    const int wv = threadIdx.x >> 6;
    if ((threadIdx.x & 63) == 0) { red[0][wv] = s; red[1][wv] = s2; }
    __syncthreads();
    s  = red[0][0] + red[0][1] + red[0][2];
    s2 = red[1][0] + red[1][1] + red[1][2];
    const float mu   = s * (1.f / CC);
    const float var  = s2 * (1.f / CC) - mu * mu;
    const float rstd = rsqrtf(var + 1e-5f);
    const float hval = (hv - mu) * rstd * gamma[c] + beta[c];
    const size_t off = ((row >> 5) * 12 + (c >> 4)) * 512 +
                       ((row & 31) + ((c >> 3) & 1) * 32) * 8 + (c & 7);
    hfrag[off] = f2bf(hval);
}

// ---------------------------------------------------------------------------
extern "C" void kernel_launch(void* const* d_in, const int* in_sizes, int n_in,
                              void* d_out, int out_size, void* d_ws, size_t ws_size,
                              hipStream_t stream)
{
    const float* x    = (const float*)d_in[0];
    const float* Wk   = (const float*)d_in[1];
    const float* Wv   = (const float*)d_in[2];
    const float* Wr   = (const float*)d_in[3];
    const float* Wo   = (const float*)d_in[4];
    const float* ln_g = (const float*)d_in[5];
    const float* ln_b = (const float*)d_in[6];
    const float* wdec = (const float*)d_in[7];
    const float* u    = (const float*)d_in[8];

    unsigned short* kbf   = (unsigned short*)d_ws;
    unsigned short* vbf   = kbf + NNELE;
    unsigned short* rbf   = vbf + NNELE;
    unsigned short* xfrag = rbf + NNELE;
    unsigned short* wfrag = xfrag + NNELE;       // 4*WCH bf16
    float* sp = (float*)xfrag;                   // alias: states after proj
    float* sq = sp + NSTATE;
    float* so = sq + NSTATE;
    unsigned short* hfrag = kbf;                 // alias: h after scans
    unsigned short* yfwd  = (unsigned short*)d_out;  // bf16 staging in d_out
    unsigned short* ybwd  = yfwd + NNELE;
    float* out = (float*)d_out;

    wcvt_frag<<<72, 256, 0, stream>>>(Wk, Wv, Wr, Wo, wfrag);
    xcvt_frag<<<dim3(TPIX / 32, BB), 256, 0, stream>>>(x, xfrag);

    proj_mfma32<<<dim3((BB * TPIX) / 128, 1, 3), 512, 0, stream>>>(
        xfrag, wfrag, kbf, vbf, rbf);

    const int nth = (int)NSTATE;
    wkv_chunk_kernel<<<nth / 256, 256, 0, stream>>>(kbf, vbf, wdec, sp, sq, so);
    wkv_prefix_kernel<<<(2 * BB * CC + 255) / 256, 256, 0, stream>>>(sp, sq, so, wdec);
    wkv_emit_kernel<<<nth / 256, 256, 0, stream>>>(kbf, vbf, wdec, u, sp, sq, so, yfwd, ybwd);

    ln_kernel<<<BB * TPIX, 192, 0, stream>>>(rbf, yfwd, ybwd, ln_g, ln_b, hfrag);

    outproj_mfma32<<<(BB * TPIX) / 128, 512, 0, stream>>>(hfrag, wfrag + 3 * WCH, out);
}

// Round 16
// 131.876 us; speedup vs baseline: 1.1130x; 1.0282x over previous
//
#include <hip/hip_runtime.h>
#include <hip/hip_bf16.h>

#define BB 16
#define CC 192
#define TPIX 3136                       // 56*56
#define NCH 49                          // chunks per sequence
#define CHL 64                          // chunk length (49*64 = 3136)
#define NNELE ((size_t)BB * TPIX * CC)  // 9,633,792 elements per [B,T,C] buffer
#define NSTATE ((size_t)2 * BB * NCH * CC)  // 301,056 chunk states
#define WCH (CC * CC)                   // 36864 elems per W matrix

typedef __attribute__((ext_vector_type(8))) short bf16x8;
typedef __attribute__((ext_vector_type(4))) float f32x4;
typedef __attribute__((ext_vector_type(16))) float f32x16;

__device__ __forceinline__ unsigned short f2bf(float f) {
    __hip_bfloat16 b = __float2bfloat16(f);          // HW RNE cvt
    return *reinterpret_cast<unsigned short*>(&b);
}
__device__ __forceinline__ float bf2f(unsigned short h) {
    union { unsigned u; float f; } v; v.u = ((unsigned)h) << 16;
    return v.f;
}

// Fragment-major layout: element (row, col) of a rows x 192 matrix lives at
//   tile = (row>>5)*12 + (col>>4);  lane = (row&31) + ((col>>3)&1)*32;  elem = col&7
//   offset = tile*512 + lane*8 + elem

// ---------------------------------------------------------------------------
// W convert -> fragment-major bf16, 4 matrices (k,v,r,o).
// ---------------------------------------------------------------------------
__global__ __launch_bounds__(256) void wcvt_frag(
    const float* __restrict__ Wk, const float* __restrict__ Wv,
    const float* __restrict__ Wr, const float* __restrict__ Wo,
    unsigned short* __restrict__ wfrag)
{
    const int id = blockIdx.x * 256 + threadIdx.x;    // 0..18431
    const int m = id / 4608;
    const int r = id % 4608;
    const int tile = r >> 6;          // 0..71  (= dr*12 + tk)
    const int lane = r & 63;
    const int dr = tile / 12, tk = tile % 12;
    const int d = dr * 32 + (lane & 31);
    const int c = tk * 16 + (lane >> 5) * 8;
    const float* W = (m == 0) ? Wk : (m == 1) ? Wv : (m == 2) ? Wr : Wo;
    const float4 a = *(const float4*)&W[d * CC + c];
    const float4 b = *(const float4*)&W[d * CC + c + 4];
    bf16x8 o;
    o[0] = (short)f2bf(a.x); o[1] = (short)f2bf(a.y);
    o[2] = (short)f2bf(a.z); o[3] = (short)f2bf(a.w);
    o[4] = (short)f2bf(b.x); o[5] = (short)f2bf(b.y);
    o[6] = (short)f2bf(b.z); o[7] = (short)f2bf(b.w);
    *(bf16x8*)&wfrag[(size_t)m * WCH + (size_t)tile * 512 + lane * 8] = o;
}

// ---------------------------------------------------------------------------
// x transpose+convert -> fragment-major bf16. Block = 32 t x 192 c for one b.
// ---------------------------------------------------------------------------
__global__ __launch_bounds__(256) void xcvt_frag(
    const float* __restrict__ x, unsigned short* __restrict__ xfrag)
{
    const int t0 = blockIdx.x * 32;
    const int b  = blockIdx.y;
    __shared__ float ls[CC][33];
    const int tid = threadIdx.x;
#pragma unroll
    for (int it = 0; it < 6; ++it) {
        const int c  = it * 32 + (tid >> 3);
        const int t4 = (tid & 7) * 4;
        *(float4*)&ls[c][t4] =
            *(const float4*)&x[((size_t)b * CC + c) * TPIX + t0 + t4];
    }
    __syncthreads();
    const size_t tbase = ((size_t)(b * TPIX + t0) >> 5) * 12;
#pragma unroll
    for (int it = 0; it < 3; ++it) {
        const int id = it * 256 + tid;          // 0..767
        const int tk = id >> 6;
        const int lane = id & 63;
        const int r32 = lane & 31;
        const int c0 = tk * 16 + (lane >> 5) * 8;
        bf16x8 o;
#pragma unroll
        for (int e = 0; e < 8; ++e)
            o[e] = (short)f2bf(ls[c0 + e][r32]);
        *(bf16x8*)&xfrag[(tbase + tk) * 512 + lane * 8] = o;
    }
}

// ---------------------------------------------------------------------------
// Fused projections, 32x32x16 MFMA. ALL 12 x-fragments issued up front so
// their L3 latency hides under the 73.7KB W staging + barrier. k,v written
// [t][c] for the scan; r written FRAGMENT-MAJOR for the fused outproj.
// grid (392, 1, 3) x 512.
// ---------------------------------------------------------------------------
__global__ __launch_bounds__(512, 4) void proj_mfma32(
    const unsigned short* __restrict__ xfrag,
    const unsigned short* __restrict__ wfrag,
    unsigned short* __restrict__ kbf, unsigned short* __restrict__ vbf,
    unsigned short* __restrict__ rfrag)
{
    __shared__ unsigned short wlds[WCH];     // 73728 bytes
    const int tid  = threadIdx.x;
    const int lane = tid & 63;
    const int wv   = tid >> 6;               // 0..7
    const int tw   = wv >> 1;                // 0..3
    const int dwav = wv & 1;
    const int l31  = lane & 31;
    const int kh   = lane >> 5;
    const int m    = blockIdx.z;

    const size_t row0 = (size_t)blockIdx.x * 128 + tw * 32;
    const size_t xtb  = (row0 >> 5) * 12;

    // issue all 12 A-fragment loads first (oldest in the vmcnt queue)
    bf16x8 xf[12];
#pragma unroll
    for (int ks = 0; ks < 12; ++ks)
        xf[ks] = *(const bf16x8*)&xfrag[(xtb + ks) * 512 + lane * 8];

    // stage W; its ds_writes + barrier absorb the xf latency
    const unsigned short* wm = wfrag + (size_t)m * WCH;
#pragma unroll
    for (int it = 0; it < 9; ++it) {
        const int off = (it * 512 + tid) * 8;
        *(bf16x8*)&wlds[off] = *(const bf16x8*)&wm[off];
    }
    __syncthreads();

    f32x16 acc[3];
#pragma unroll
    for (int nn = 0; nn < 3; ++nn)
#pragma unroll
        for (int e = 0; e < 16; ++e) acc[nn][e] = 0.f;

#pragma unroll
    for (int ks = 0; ks < 12; ++ks) {
        bf16x8 wf[3];
#pragma unroll
        for (int nn = 0; nn < 3; ++nn)
            wf[nn] = *(const bf16x8*)&wlds[((dwav * 3 + nn) * 12 + ks) * 512 + lane * 8];
#pragma unroll
        for (int nn = 0; nn < 3; ++nn)
            acc[nn] = __builtin_amdgcn_mfma_f32_32x32x16_bf16(
                xf[ks], wf[nn], acc[nn], 0, 0, 0);
    }

    if (m == 2) {
        // r -> fragment-major (row = t, col = d)
#pragma unroll
        for (int nn = 0; nn < 3; ++nn) {
            const int d = dwav * 96 + nn * 32 + l31;
            const size_t tb = ((row0 >> 5) * 12 + (d >> 4)) * 512 +
                              (size_t)(((d >> 3) & 1) * 32) * 8 + (d & 7);
#pragma unroll
            for (int q = 0; q < 16; ++q) {
                const int tq = (q & 3) + 8 * (q >> 2) + 4 * kh;
                rfrag[tb + tq * 8] = f2bf(acc[nn][q]);
            }
        }
    } else {
        unsigned short* om = (m == 0) ? kbf : vbf;
#pragma unroll
        for (int nn = 0; nn < 3; ++nn) {
            const int d = dwav * 96 + nn * 32 + l31;
#pragma unroll
            for (int q = 0; q < 16; ++q) {
                const int t = (q & 3) + 8 * (q >> 2) + 4 * kh;
                om[(row0 + t) * CC + d] = f2bf(acc[nn][q]);
            }
        }
    }
}

// ---------------------------------------------------------------------------
// WKV chunked scan pass 1 (bf16 k/v, [t][c] layout). (num,den)=(p,q)*e^o.
// ---------------------------------------------------------------------------
__global__ __launch_bounds__(256) void wkv_chunk_kernel(
    const unsigned short* __restrict__ kb, const unsigned short* __restrict__ vb,
    const float* __restrict__ wdec,
    float* __restrict__ sp, float* __restrict__ sq, float* __restrict__ so)
{
    const int gid = blockIdx.x * 256 + threadIdx.x;
    const int c  = gid % CC;
    const int r  = gid / CC;
    const int ch = r % NCH;
    const int r2 = r / NCH;
    const int b  = r2 % BB;
    const int dir = r2 / BB;

    const float w = -__expf(wdec[c]);
    const int tstart = dir ? (TPIX - 1 - ch * CHL) : (ch * CHL);
    const long stride = dir ? -(long)CC : (long)CC;
    long idx = ((long)b * TPIX + tstart) * CC + c;

    float p = 0.f, q = 0.f, o = -1e38f;
#pragma unroll 4
    for (int j = 0; j < CHL; ++j) {
        const float kt = bf2f(kb[idx]), vt = bf2f(vb[idx]);
        const float wo  = w + o;
        const float no2 = fmaxf(wo, kt);
        const float A2  = __expf(wo - no2);
        const float B2  = __expf(kt - no2);
        p = A2 * p + B2 * vt;
        q = A2 * q + B2;
        o = no2;
        idx += stride;
    }
    sp[gid] = p; sq[gid] = q; so[gid] = o;
}

// Pass 2: in-place exclusive prefix over chunk states per (dir,b,c).
__global__ __launch_bounds__(256) void wkv_prefix_kernel(
    float* __restrict__ sp, float* __restrict__ sq, float* __restrict__ so,
    const float* __restrict__ wdec)
{
    const int tid = blockIdx.x * 256 + threadIdx.x;
    if (tid >= 2 * BB * CC) return;
    const int c = tid % CC;
    const int g = tid / CC;
    const float w  = -__expf(wdec[c]);
    const float wL = w * CHL;

    float P = 0.f, Q = 0.f, O = -1e38f;
    size_t idx = (size_t)g * NCH * CC + c;
    for (int ch = 0; ch < NCH; ++ch) {
        const float pl = sp[idx], ql = sq[idx], ol = so[idx];
        sp[idx] = P; sq[idx] = Q; so[idx] = O;
        const float Ow = O + wL;
        const float no = fmaxf(Ow, ol);
        const float A  = __expf(Ow - no);
        const float Bf = __expf(ol - no);
        P = A * P + Bf * pl;
        Q = A * Q + Bf * ql;
        O = no;
        idx += CC;
    }
}

// Pass 3: re-scan chunk from exclusive prefix; write bf16(0.5*y) in
// FRAGMENT-MAJOR layout to the direction's own buffer (each element once).
__global__ __launch_bounds__(256) void wkv_emit_kernel(
    const unsigned short* __restrict__ kb, const unsigned short* __restrict__ vb,
    const float* __restrict__ wdec, const float* __restrict__ ubias,
    const float* __restrict__ sp, const float* __restrict__ sq,
    const float* __restrict__ so,
    unsigned short* __restrict__ yfwd, unsigned short* __restrict__ ybwd)
{
    const int gid = blockIdx.x * 256 + threadIdx.x;
    const int c  = gid % CC;
    const int r  = gid / CC;
    const int ch = r % NCH;
    const int r2 = r / NCH;
    const int b  = r2 % BB;
    const int dir = r2 / BB;

    const float w = -__expf(wdec[c]);
    const float u = ubias[c];
    const int tstart = dir ? (TPIX - 1 - ch * CHL) : (ch * CHL);
    const long stride = dir ? -(long)CC : (long)CC;
    const int rstep = dir ? -1 : 1;
    long idx = ((long)b * TPIX + tstart) * CC + c;
    long row = (long)b * TPIX + tstart;          // flattened row (TPIX%32==0)
    unsigned short* yout = dir ? ybwd : yfwd;
    const int ctile = c >> 4;
    const int clane = ((c >> 3) & 1) * 32;
    const int ce    = c & 7;

    float p = sp[gid], q = sq[gid], o = so[gid];
#pragma unroll 2
    for (int j = 0; j < CHL; ++j) {
        const float kt = bf2f(kb[idx]), vt = bf2f(vb[idx]);
        const float uk  = u + kt;
        const float no  = fmaxf(o, uk);
        const float A   = __expf(o - no);
        const float Bw  = __expf(uk - no);
        const float num = A * p + Bw * vt;
        const float den = A * q + Bw;
        const size_t off = ((size_t)(row >> 5) * 12 + ctile) * 512 +
                           (size_t)((row & 31) + clane) * 8 + ce;
        yout[off] = f2bf(0.5f * __fdividef(num, den));
        const float wo  = w + o;
        const float no2 = fmaxf(wo, kt);
        const float A2  = __expf(wo - no2);
        const float B2  = __expf(kt - no2);
        p = A2 * p + B2 * vt;
        q = A2 * q + B2;
        o = no2;
        idx += stride;
        row += rstep;
    }
}

// ---------------------------------------------------------------------------
// FUSED output stage: h = LN(sigmoid(r)*(yf+yb)) computed in-register, then
// out[b,d,t] = h @ Wo^T via 32x32x16 MFMA. Row stats need only one
// shfl_xor(32): row r's 192 channels live in lanes l31 and l31+32 across
// the 12 k-fragments. Wo + gamma/beta staged in LDS. grid 392 x 512.
// ---------------------------------------------------------------------------
__global__ __launch_bounds__(512) void outproj_ln_mfma32(
    const unsigned short* __restrict__ yfwd, const unsigned short* __restrict__ ybwd,
    const unsigned short* __restrict__ rfrag,
    const float* __restrict__ gamma, const float* __restrict__ beta,
    const unsigned short* __restrict__ wo,
    float* __restrict__ out)
{
    __shared__ unsigned short wlds[WCH];
    __shared__ float gblds[CC];
    __shared__ float bblds[CC];
    const int tid  = threadIdx.x;
    const int lane = tid & 63;
    const int wv   = tid >> 6;
    const int tw   = wv >> 1;
    const int dwav = wv & 1;
    const int l31  = lane & 31;
    const int kh   = lane >> 5;

#pragma unroll
    for (int it = 0; it < 9; ++it) {
        const int off = (it * 512 + tid) * 8;
        *(bf16x8*)&wlds[off] = *(const bf16x8*)&wo[off];
    }
    if (tid < CC) { gblds[tid] = gamma[tid]; bblds[tid] = beta[tid]; }
    __syncthreads();

    const size_t row0 = (size_t)blockIdx.x * 128 + tw * 32;
    const size_t htb  = (row0 >> 5) * 12;

    // hv = sigmoid(r) * (yf + yb); keep bf16 fragments + fp32 stats
    bf16x8 hvb[12];
    float s = 0.f, s2 = 0.f;
#pragma unroll
    for (int ks = 0; ks < 12; ++ks) {
        const size_t fo = (htb + ks) * 512 + lane * 8;
        const bf16x8 yf = *(const bf16x8*)&yfwd[fo];
        const bf16x8 yb = *(const bf16x8*)&ybwd[fo];
        const bf16x8 rv = *(const bf16x8*)&rfrag[fo];
        bf16x8 hb;
#pragma unroll
        for (int e = 0; e < 8; ++e) {
            const float xb = bf2f((unsigned short)yf[e]) + bf2f((unsigned short)yb[e]);
            const float rr = bf2f((unsigned short)rv[e]);
            const float h  = xb / (1.f + __expf(-rr));
            s += h; s2 += h * h;
            hb[e] = (short)f2bf(h);
        }
        hvb[ks] = hb;
    }
    s  += __shfl_xor(s, 32);
    s2 += __shfl_xor(s2, 32);
    const float mu   = s * (1.f / CC);
    const float var  = s2 * (1.f / CC) - mu * mu;
    const float rstd = rsqrtf(var + 1e-5f);

    // normalize in-register -> MFMA A-fragments
#pragma unroll
    for (int ks = 0; ks < 12; ++ks) {
        const int cbase = ks * 16 + kh * 8;
        const f32x4 g0 = *(const f32x4*)&gblds[cbase];
        const f32x4 g1 = *(const f32x4*)&gblds[cbase + 4];
        const f32x4 b0 = *(const f32x4*)&bblds[cbase];
        const f32x4 b1 = *(const f32x4*)&bblds[cbase + 4];
        bf16x8 hb = hvb[ks];
#pragma unroll
        for (int e = 0; e < 4; ++e) {
            const float h0 = (bf2f((unsigned short)hb[e]) - mu) * rstd * g0[e] + b0[e];
            const float h1 = (bf2f((unsigned short)hb[e + 4]) - mu) * rstd * g1[e] + b1[e];
            hb[e]     = (short)f2bf(h0);
            hb[e + 4] = (short)f2bf(h1);
        }
        hvb[ks] = hb;
    }

    f32x16 acc[3];
#pragma unroll
    for (int nn = 0; nn < 3; ++nn)
#pragma unroll
        for (int e = 0; e < 16; ++e) acc[nn][e] = 0.f;

#pragma unroll
    for (int ks = 0; ks < 12; ++ks) {
        bf16x8 wf[3];
#pragma unroll
        for (int nn = 0; nn < 3; ++nn)
            wf[nn] = *(const bf16x8*)&wlds[((dwav * 3 + nn) * 12 + ks) * 512 + lane * 8];
#pragma unroll
        for (int nn = 0; nn < 3; ++nn)
            acc[nn] = __builtin_amdgcn_mfma_f32_32x32x16_bf16(
                hvb[ks], wf[nn], acc[nn], 0, 0, 0);
    }

#pragma unroll
    for (int nn = 0; nn < 3; ++nn) {
        const int d = dwav * 96 + nn * 32 + l31;
#pragma unroll
        for (int q2 = 0; q2 < 4; ++q2) {
            const size_t grow = row0 + 4 * kh + 8 * q2;
            const int b  = (int)(grow / TPIX);
            const int tl = (int)(grow % TPIX);
            f32x4 v4 = {acc[nn][q2 * 4 + 0], acc[nn][q2 * 4 + 1],
                        acc[nn][q2 * 4 + 2], acc[nn][q2 * 4 + 3]};
            *(f32x4*)&out[((size_t)b * CC + d) * TPIX + tl] = v4;
        }
    }
}

// ---------------------------------------------------------------------------
extern "C" void kernel_launch(void* const* d_in, const int* in_sizes, int n_in,
                              void* d_out, int out_size, void* d_ws, size_t ws_size,
                              hipStream_t stream)
{
    const float* x    = (const float*)d_in[0];
    const float* Wk   = (const float*)d_in[1];
    const float* Wv   = (const float*)d_in[2];
    const float* Wr   = (const float*)d_in[3];
    const float* Wo   = (const float*)d_in[4];
    const float* ln_g = (const float*)d_in[5];
    const float* ln_b = (const float*)d_in[6];
    const float* wdec = (const float*)d_in[7];
    const float* u    = (const float*)d_in[8];

    unsigned short* kbf   = (unsigned short*)d_ws;
    unsigned short* vbf   = kbf + NNELE;
    unsigned short* rfrag = vbf + NNELE;
    unsigned short* xfrag = rfrag + NNELE;
    unsigned short* wfrag = xfrag + NNELE;       // 4*WCH bf16
    unsigned short* yfwd  = wfrag + 4 * WCH;     // fragment-major y staging
    unsigned short* ybwd  = yfwd + NNELE;        // (total ws use ~115.9 MB)
    float* sp = (float*)xfrag;                   // alias: states after proj
    float* sq = sp + NSTATE;
    float* so = sq + NSTATE;
    float* out = (float*)d_out;

    wcvt_frag<<<72, 256, 0, stream>>>(Wk, Wv, Wr, Wo, wfrag);
    xcvt_frag<<<dim3(TPIX / 32, BB), 256, 0, stream>>>(x, xfrag);

    proj_mfma32<<<dim3((BB * TPIX) / 128, 1, 3), 512, 0, stream>>>(
        xfrag, wfrag, kbf, vbf, rfrag);

    const int nth = (int)NSTATE;
    wkv_chunk_kernel<<<nth / 256, 256, 0, stream>>>(kbf, vbf, wdec, sp, sq, so);
    wkv_prefix_kernel<<<(2 * BB * CC + 255) / 256, 256, 0, stream>>>(sp, sq, so, wdec);
    wkv_emit_kernel<<<nth / 256, 256, 0, stream>>>(kbf, vbf, wdec, u, sp, sq, so, yfwd, ybwd);

    outproj_ln_mfma32<<<(BB * TPIX) / 128, 512, 0, stream>>>(
        yfwd, ybwd, rfrag, ln_g, ln_b, wfrag + 3 * WCH, out);
}